// Round 3
// baseline (1747.615 us; speedup 1.0000x reference)
//
#include <hip/hip_runtime.h>
#include <hip/hip_cooperative_groups.h>
#include <stdint.h>

namespace cg = cooperative_groups;

// SparseDecoder: 4-layer masked MLP forward.
//   x:[64,512] fp32; layer i: K=SIZES[i] -> N=SIZES[i+1]
//   z_i = x @ (W_i * mask_i)^T + b_i ; relu between layers (applied on READ
//   by the next layer's GEMM; each GEMM stores pre-activation z).
//
// ROUND 3 THEORY: round-2 profile: 1095 us, 1.29 TB/s (16% HBM), VALUBusy
// 4.9%, MfmaUtil 0.8%, VGPR=76 -> LATENCY-BOUND: compiler serialized the
// 24 reg-loads per k-step (too few VGPRs to pipeline), ~1-2 KB in flight
// per wave vs ~17 KB/CU needed for 6.3 TB/s. Fix: global_load_lds DMA
// staging (zero VGPR cost) with per-wave double-buffered LDS (32 KB/wave),
// counted s_waitcnt vmcnt(16) (never 0 in steady state), no __syncthreads.
// One 64-thread block = one wave = one 64n x 64batch tile. LDS 128B rows
// would be a 16-way bank conflict; fixed by granule-level XOR swizzle
// applied on the GLOBAL source address (gll dest must stay linear) and the
// matching XOR on the ds_read side. Work split: tiles == 1024 waves exactly
// on layers 1-3 (nk=8/16/8/4), halving atomic count vs round 2 (tests the
// "atomics cause the 679 MB WRITE_SIZE" theory).
//
// MASK DTYPE: runtime probe (int32 bools have zero upper bytes) selects the
// int32 fast path; u8 layout falls back to the round-2 register path.

typedef short bf16x8 __attribute__((ext_vector_type(8)));   // 8 bf16 (4 VGPRs)
typedef float f32x4  __attribute__((ext_vector_type(4)));   // 4 fp32 acc

__device__ __forceinline__ unsigned short f2bf(float f) {
    // round-to-nearest-even fp32 -> bf16 (finite inputs)
    unsigned int u = __float_as_uint(f);
    return (unsigned short)((u + 0x7FFFu + ((u >> 16) & 1u)) >> 16);
}

__device__ __forceinline__ unsigned int bfpair(float lo, float hi) {
    return (unsigned int)f2bf(lo) | ((unsigned int)f2bf(hi) << 16);
}

__device__ __forceinline__ bf16x8 pack8(const float4& a, const float4& b) {
    union { unsigned int u[4]; bf16x8 v; } r;
    r.u[0] = bfpair(a.x, a.y);
    r.u[1] = bfpair(a.z, a.w);
    r.u[2] = bfpair(b.x, b.y);
    r.u[3] = bfpair(b.z, b.w);
    return r.v;
}

// 16B global -> LDS DMA. dst must be wave-uniform (HW writes lane l at
// dst + l*16); src is per-lane.
__device__ __forceinline__ void gll16(const void* src, void* dst) {
    __builtin_amdgcn_global_load_lds(
        (const __attribute__((address_space(1))) unsigned int*)src,
        (__attribute__((address_space(3))) unsigned int*)dst, 16, 0, 0);
}

// Stage one 64row x 32k chunk of W(fp32) + mask(i32) into LDS.
// LDS layout: row-major 128B rows; within a row, 16B granule g of the
// global data sits at position g ^ (row&7) (bank-spread swizzle).
// gll writes linearly (instr i, lane l -> row i*8 + l/8, pos l%8), so the
// swizzle is realized by pre-swizzling the per-lane GLOBAL address:
// lane l sources granule (l%8) ^ ((l/8)&7) of its row.
__device__ __forceinline__ void stage_chunk(
    const float* wsrc, const int* msrc, int K, float* lw, int* lm)
{
    #pragma unroll
    for (int i = 0; i < 8; ++i) {
        gll16(wsrc + (size_t)i * 8 * K, lw + i * 256);
        gll16(msrc + (size_t)i * 8 * K, lm + i * 256);
    }
}

// ---------- LDS-staged per-wave GEMM tile (int32-mask fast path) ----------
// One wave: 64n x 64b tile over K-range [kbeg, kbeg+kper).
// lwb/lmb: this wave's LDS buffers, 2 x 2048 elems each.
template <int RELU>
__device__ __forceinline__ void gemm_tile_lds(
    const float* __restrict__ X, const float* __restrict__ W,
    const int* __restrict__ M, float* __restrict__ Z,
    int N, int K, int kbeg, int kper, int n0,
    int l, int lr, int q, float* lwb, int* lmb)
{
    const int nc  = kper >> 5;         // 32-k chunks (always >= 2, even)
    const int rr  = l >> 3;            // staging: row-within-8
    const int gl4 = (((l & 7) ^ (rr & 7)) << 2);  // swizzled granule offset

    f32x4 acc[4][4];
    #pragma unroll
    for (int i = 0; i < 4; ++i)
        #pragma unroll
        for (int j = 0; j < 4; ++j) acc[i][j] = (f32x4){0.f, 0.f, 0.f, 0.f};

    const float* wsrc0 = W + (size_t)(n0 + rr) * K + kbeg + gl4;
    const int*   msrc0 = M + (size_t)(n0 + rr) * K + kbeg + gl4;
    const float* xb    = X + (size_t)lr * K + q * 8;

    // prologue: chunk 0 -> buffer 0
    stage_chunk(wsrc0, msrc0, K, lwb, lmb);

    #pragma unroll 1
    for (int c = 0; c < nc; ++c) {
        const int p  = c & 1;
        const int kk = kbeg + c * 32;

        // ---- issue x loads for this chunk (oldest in the vmcnt window) ----
        float4 xv0[4], xv1[4];
        #pragma unroll
        for (int bg = 0; bg < 4; ++bg) {
            const float* xp = xb + kk + (size_t)bg * 16 * K;
            xv0[bg] = *(const float4*)xp;
            xv1[bg] = *(const float4*)(xp + 4);
        }

        // ---- prefetch chunk c+1 into the other buffer, counted wait ----
        if (c + 1 < nc) {
            stage_chunk(wsrc0 + (c + 1) * 32, msrc0 + (c + 1) * 32, K,
                        lwb + (p ^ 1) * 2048, lmb + (p ^ 1) * 2048);
            // 16 newest = chunk c+1's DMA; chunk c's DMA + x are older -> done.
            asm volatile("s_waitcnt vmcnt(16)" ::: "memory");
        } else {
            asm volatile("s_waitcnt vmcnt(0)" ::: "memory");
        }

        // ---- B fragments from x regs ----
        bf16x8 bfr[4];
        #pragma unroll
        for (int bg = 0; bg < 4; ++bg) {
            float4 x0 = xv0[bg], x1 = xv1[bg];
            if (RELU) {
                x0.x = fmaxf(x0.x, 0.f); x0.y = fmaxf(x0.y, 0.f);
                x0.z = fmaxf(x0.z, 0.f); x0.w = fmaxf(x0.w, 0.f);
                x1.x = fmaxf(x1.x, 0.f); x1.y = fmaxf(x1.y, 0.f);
                x1.z = fmaxf(x1.z, 0.f); x1.w = fmaxf(x1.w, 0.f);
            }
            bfr[bg] = pack8(x0, x1);
        }

        // ---- A fragments from LDS (swizzled read) + MFMA ----
        const float* lw = lwb + p * 2048;
        const int*   lm = lmb + p * 2048;
        const int s  = lr & 7;
        const int p0 = (((2 * q)     ^ s) << 2);   // fp32 offset of granule 2q
        const int p1 = (((2 * q + 1) ^ s) << 2);   // and 2q+1
        #pragma unroll
        for (int ng = 0; ng < 4; ++ng) {
            const int R = ng * 16 + lr;            // R&7 == lr&7
            const float* wr = lw + R * 32;
            const int*   mr = lm + R * 32;
            float4 w0 = *(const float4*)(wr + p0);
            float4 w1 = *(const float4*)(wr + p1);
            int4  mm0 = *(const int4*)(mr + p0);
            int4  mm1 = *(const int4*)(mr + p1);
            w0.x = mm0.x ? w0.x : 0.f;
            w0.y = mm0.y ? w0.y : 0.f;
            w0.z = mm0.z ? w0.z : 0.f;
            w0.w = mm0.w ? w0.w : 0.f;
            w1.x = mm1.x ? w1.x : 0.f;
            w1.y = mm1.y ? w1.y : 0.f;
            w1.z = mm1.z ? w1.z : 0.f;
            w1.w = mm1.w ? w1.w : 0.f;
            bf16x8 a = pack8(w0, w1);
            #pragma unroll
            for (int bg = 0; bg < 4; ++bg)
                acc[ng][bg] = __builtin_amdgcn_mfma_f32_16x16x32_bf16(
                    a, bfr[bg], acc[ng][bg], 0, 0, 0);
        }
    }

    // --- epilogue: D layout col=lane&15 (batch), row=quad*4+reg (n) ---
    #pragma unroll
    for (int ng = 0; ng < 4; ++ng) {
        #pragma unroll
        for (int bg = 0; bg < 4; ++bg) {
            int b = bg * 16 + lr;
            float* zp = Z + (size_t)b * N + n0 + ng * 16 + q * 4;
            #pragma unroll
            for (int r = 0; r < 4; ++r) atomicAdd(&zp[r], acc[ng][bg][r]);
        }
    }
}

// ---------- register-path GEMM (u8-mask fallback; round-2 proven) ----------
template <int MU8, int RELU>
__device__ __forceinline__ void gemm_loop_reg(
    const float* __restrict__ X, const float* __restrict__ W,
    const unsigned char* __restrict__ Mk,
    int K, int kbeg, int kend, int n0, int lr, int quad, f32x4 (&acc)[4][4])
{
    const int* __restrict__ Mk32 = (const int*)Mk;
    const size_t xoff = (size_t)lr * K + quad * 8;
    const size_t woff = (size_t)(n0 + lr) * K + quad * 8;

    #pragma unroll 1
    for (int k = kbeg; k < kend; k += 32) {
        bf16x8 bfr[4];
        #pragma unroll
        for (int bg = 0; bg < 4; ++bg) {
            const float* xp = X + xoff + (size_t)bg * 16 * K + k;
            float4 x0 = *(const float4*)xp;
            float4 x1 = *(const float4*)(xp + 4);
            if (RELU) {
                x0.x = fmaxf(x0.x, 0.f); x0.y = fmaxf(x0.y, 0.f);
                x0.z = fmaxf(x0.z, 0.f); x0.w = fmaxf(x0.w, 0.f);
                x1.x = fmaxf(x1.x, 0.f); x1.y = fmaxf(x1.y, 0.f);
                x1.z = fmaxf(x1.z, 0.f); x1.w = fmaxf(x1.w, 0.f);
            }
            bfr[bg] = pack8(x0, x1);
        }
        #pragma unroll
        for (int ng = 0; ng < 4; ++ng) {
            size_t e = woff + (size_t)ng * 16 * K + k;
            float4 w0 = *(const float4*)(W + e);
            float4 w1 = *(const float4*)(W + e + 4);
            if (MU8) {
                uint2 m8 = *(const uint2*)(Mk + e);
                w0.x = (m8.x & 0x000000FFu) ? w0.x : 0.f;
                w0.y = (m8.x & 0x0000FF00u) ? w0.y : 0.f;
                w0.z = (m8.x & 0x00FF0000u) ? w0.z : 0.f;
                w0.w = (m8.x & 0xFF000000u) ? w0.w : 0.f;
                w1.x = (m8.y & 0x000000FFu) ? w1.x : 0.f;
                w1.y = (m8.y & 0x0000FF00u) ? w1.y : 0.f;
                w1.z = (m8.y & 0x00FF0000u) ? w1.z : 0.f;
                w1.w = (m8.y & 0xFF000000u) ? w1.w : 0.f;
            } else {
                int4 mm0 = *(const int4*)(Mk32 + e);
                int4 mm1 = *(const int4*)(Mk32 + e + 4);
                w0.x = mm0.x ? w0.x : 0.f;
                w0.y = mm0.y ? w0.y : 0.f;
                w0.z = mm0.z ? w0.z : 0.f;
                w0.w = mm0.w ? w0.w : 0.f;
                w1.x = mm1.x ? w1.x : 0.f;
                w1.y = mm1.y ? w1.y : 0.f;
                w1.z = mm1.z ? w1.z : 0.f;
                w1.w = mm1.w ? w1.w : 0.f;
            }
            bf16x8 a = pack8(w0, w1);
            #pragma unroll
            for (int bg = 0; bg < 4; ++bg)
                acc[ng][bg] = __builtin_amdgcn_mfma_f32_16x16x32_bf16(
                    a, bfr[bg], acc[ng][bg], 0, 0, 0);
        }
    }
}

template <int MU8, int RELU>
__device__ __forceinline__ void gemm_tile_reg(
    const float* __restrict__ X, const float* __restrict__ W,
    const unsigned char* __restrict__ Mk,
    float* __restrict__ Z, int N, int K,
    int kbeg, int kend, int n0, int lr, int quad)
{
    f32x4 acc[4][4];
    #pragma unroll
    for (int i = 0; i < 4; ++i)
        #pragma unroll
        for (int j = 0; j < 4; ++j) acc[i][j] = (f32x4){0.f, 0.f, 0.f, 0.f};

    gemm_loop_reg<MU8, RELU>(X, W, Mk, K, kbeg, kend, n0, lr, quad, acc);

    #pragma unroll
    for (int ng = 0; ng < 4; ++ng) {
        #pragma unroll
        for (int bg = 0; bg < 4; ++bg) {
            int b = bg * 16 + lr;
            float* zp = Z + (size_t)b * N + n0 + ng * 16 + quad * 4;
            #pragma unroll
            for (int r = 0; r < 4; ++r) atomicAdd(&zp[r], acc[ng][bg][r]);
        }
    }
}

// ---------- per-layer work distribution ----------
// tiles = ntx * nk; tile t: n0 = (t & (ntx-1))*64, kbeg = (t >> sh)*kper.
template <int RELU>
__device__ __forceinline__ void run_layer(
    const float* __restrict__ X, const float* __restrict__ W,
    const unsigned char* __restrict__ Mk, int mu8,
    float* __restrict__ Z, int N, int K, int nk, int kper,
    int wid, int nw, int l, int lr, int quad, float* lwb, int* lmb)
{
    const int ntx    = N >> 6;
    const int sh     = 31 - __clz(ntx);
    const int ntiles = ntx * nk;
    for (int t = wid; t < ntiles; t += nw) {
        int n0   = (t & (ntx - 1)) << 6;
        int kbeg = (t >> sh) * kper;
        if (mu8)
            gemm_tile_reg<1, RELU>(X, W, Mk, Z, N, K, kbeg, kbeg + kper, n0, lr, quad);
        else
            gemm_tile_lds<RELU>(X, W, (const int*)Mk, Z, N, K, kbeg, kper, n0,
                                l, lr, quad, lwb, lmb);
    }
}

// Fused persistent kernel: mask probe + bias init + 4 layers, grid.sync
// between layers. 64 threads = ONE wave per block; 32 KB LDS per block
// (private double-buffered W+mask stage; no __syncthreads anywhere).
__global__ __launch_bounds__(64, 2) void fused_mlp(
    const float* __restrict__ x,
    const float* __restrict__ W0, const float* __restrict__ b0, const unsigned char* __restrict__ m0,
    const float* __restrict__ W1, const float* __restrict__ b1, const unsigned char* __restrict__ m1,
    const float* __restrict__ W2, const float* __restrict__ b2, const unsigned char* __restrict__ m2,
    const float* __restrict__ W3, const float* __restrict__ b3, const unsigned char* __restrict__ m3,
    float* __restrict__ z0, float* __restrict__ z1,
    float* __restrict__ z2, float* __restrict__ z3)
{
    cg::grid_group grid = cg::this_grid();

    __shared__ float lwbuf[2][2048];   // W stage: 2 x 8 KB
    __shared__ int   lmbuf[2][2048];   // mask stage: 2 x 8 KB

    // ---- mask-kind probe (single wave per block; scans 4 KB of mask0;
    // u8 bools have nonzero upper bytes in ~14% of words) ----
    int any = 0;
    {
        const unsigned int* mm = (const unsigned int*)m0;
        #pragma unroll
        for (int it = 0; it < 16; ++it) {
            unsigned int v = mm[it * 64 + threadIdx.x];
            if (v & 0xFFFFFF00u) any = 1;
        }
    }
    const int mu8 = (__any(any) ? 1 : 0);

    // ---- bias init: z_i[b][n] = b_i[n], grid-stride (all sizes pow2) ----
    {
        const unsigned tr = blockIdx.x * 64u + threadIdx.x;
        const unsigned tn = gridDim.x * 64u;
        for (unsigned i = tr; i < 64u * 2048u;  i += tn) z0[i] = b0[i & 2047u];
        for (unsigned i = tr; i < 64u * 4096u;  i += tn) z1[i] = b1[i & 4095u];
        for (unsigned i = tr; i < 64u * 8192u;  i += tn) z2[i] = b2[i & 8191u];
        for (unsigned i = tr; i < 64u * 16384u; i += tn) z3[i] = b3[i & 16383u];
    }

    grid.sync();

    const int wid  = blockIdx.x;        // one wave per block
    const int nw   = gridDim.x;
    const int l    = threadIdx.x;
    const int lr   = l & 15;
    const int quad = l >> 4;
    float* lwb = &lwbuf[0][0];
    int*   lmb = &lmbuf[0][0];

    // nk per layer: tiles = {256, 1024, 1024, 1024} == waves on L1-L3.
    run_layer<0>(x,  W0, m0, mu8, z0, 2048,  512,   8,   64, wid, nw, l, lr, quad, lwb, lmb);
    grid.sync();
    run_layer<1>(z0, W1, m1, mu8, z1, 4096,  2048, 16,  128, wid, nw, l, lr, quad, lwb, lmb);
    grid.sync();
    run_layer<1>(z1, W2, m2, mu8, z2, 8192,  4096,  8,  512, wid, nw, l, lr, quad, lwb, lmb);
    grid.sync();
    run_layer<1>(z2, W3, m3, mu8, z3, 16384, 8192,  4, 2048, wid, nw, l, lr, quad, lwb, lmb);
}

// ---------------- fallback path (round-2 kernels, non-cooperative) --------

__global__ __launch_bounds__(256) void probe_mask_kind(
    const unsigned int* __restrict__ m, int* __restrict__ flag)
{
    __shared__ int s_any;
    if (threadIdx.x == 0) s_any = 0;
    __syncthreads();
    int any = 0;
    #pragma unroll
    for (int it = 0; it < 16; ++it) {
        unsigned int v = m[it * 256 + threadIdx.x];
        if (v & 0xFFFFFF00u) any = 1;
    }
    if (__any(any) && (threadIdx.x & 63) == 0) s_any = 1;
    __syncthreads();
    if (threadIdx.x == 0) flag[0] = s_any;
}

__global__ __launch_bounds__(256) void init_bias_all(
    const float* __restrict__ b0, const float* __restrict__ b1,
    const float* __restrict__ b2, const float* __restrict__ b3,
    float* __restrict__ z0, float* __restrict__ z1,
    float* __restrict__ z2, float* __restrict__ z3)
{
    int n = blockIdx.x * 256 + threadIdx.x;
    int b = blockIdx.y;
    if (n < 2048)             z0[(size_t)b * 2048  + n]           = b0[n];
    else if (n < 6144)        z1[(size_t)b * 4096  + (n - 2048)]  = b1[n - 2048];
    else if (n < 14336)       z2[(size_t)b * 8192  + (n - 6144)]  = b2[n - 6144];
    else                      z3[(size_t)b * 16384 + (n - 14336)] = b3[n - 14336];
}

__global__ __launch_bounds__(64, 2) void sparse_gemm_rf(
    const float* __restrict__ X, const float* __restrict__ W,
    const unsigned char* __restrict__ Mk, const int* __restrict__ mflag,
    float* __restrict__ Z, int N, int K, int kper, int relu_in)
{
    const int l    = threadIdx.x;
    const int lr   = l & 15;
    const int quad = l >> 4;
    const int n0   = blockIdx.x * 64;
    const int kbeg = blockIdx.y * kper;
    const int mu8  = *mflag;

    if (mu8) {
        if (relu_in) gemm_tile_reg<1, 1>(X, W, Mk, Z, N, K, kbeg, kbeg + kper, n0, lr, quad);
        else         gemm_tile_reg<1, 0>(X, W, Mk, Z, N, K, kbeg, kbeg + kper, n0, lr, quad);
    } else {
        if (relu_in) gemm_tile_reg<0, 1>(X, W, Mk, Z, N, K, kbeg, kbeg + kper, n0, lr, quad);
        else         gemm_tile_reg<0, 0>(X, W, Mk, Z, N, K, kbeg, kbeg + kper, n0, lr, quad);
    }
}

extern "C" void kernel_launch(void* const* d_in, const int* in_sizes, int n_in,
                              void* d_out, int out_size, void* d_ws, size_t ws_size,
                              hipStream_t stream) {
    // setup_inputs order: x, W0,b0,mask0, W1,b1,mask1, W2,b2,mask2, W3,b3,mask3
    const float* x  = (const float*)d_in[0];
    const float* W0 = (const float*)d_in[1];
    const float* b0 = (const float*)d_in[2];
    const unsigned char* m0 = (const unsigned char*)d_in[3];
    const float* W1 = (const float*)d_in[4];
    const float* b1 = (const float*)d_in[5];
    const unsigned char* m1 = (const unsigned char*)d_in[6];
    const float* W2 = (const float*)d_in[7];
    const float* b2 = (const float*)d_in[8];
    const unsigned char* m2 = (const unsigned char*)d_in[9];
    const float* W3 = (const float*)d_in[10];
    const float* b3 = (const float*)d_in[11];
    const unsigned char* m3 = (const unsigned char*)d_in[12];

    float* z0 = (float*)d_ws;              // [64, 2048]
    float* z1 = z0 + (size_t)64 * 2048;    // [64, 4096]
    float* z2 = z1 + (size_t)64 * 4096;    // [64, 8192]
    float* z3 = (float*)d_out;             // [64, 16384]

    // Grid: all blocks resident (cooperative requirement). 1024 blocks of
    // 64 threads = 1024 waves = 4 blocks/CU (LDS 32 KB -> max 5).
    static int blocksPerCU = -1;
    if (blocksPerCU < 0) {
        hipError_t e = hipOccupancyMaxActiveBlocksPerMultiprocessor(
            &blocksPerCU, reinterpret_cast<const void*>(&fused_mlp), 64, 0);
        if (e != hipSuccess || blocksPerCU <= 0) blocksPerCU = 4;
    }
    int G = blocksPerCU * 256;
    if (G > 1024) G = 1024;   // tiles are sized for 1024 waves

    void* args[] = {
        (void*)&x,
        (void*)&W0, (void*)&b0, (void*)&m0,
        (void*)&W1, (void*)&b1, (void*)&m1,
        (void*)&W2, (void*)&b2, (void*)&m2,
        (void*)&W3, (void*)&b3, (void*)&m3,
        (void*)&z0, (void*)&z1, (void*)&z2, (void*)&z3
    };
    hipError_t le = hipLaunchCooperativeKernel(
        reinterpret_cast<const void*>(&fused_mlp),
        dim3(G), dim3(64), args, 0, stream);

    if (le != hipSuccess) {
        // Fallback: round-2 separate-kernel register path.
        int* mflag = (int*)(z2 + (size_t)64 * 8192);
        probe_mask_kind<<<1, 256, 0, stream>>>((const unsigned int*)m0, mflag);
        init_bias_all<<<dim3(120, 64), 256, 0, stream>>>(b0, b1, b2, b3, z0, z1, z2, z3);
        sparse_gemm_rf<<<dim3(32, 8),  64, 0, stream>>>(x,  W0, m0, mflag, z0, 2048,  512,   64, 0);
        sparse_gemm_rf<<<dim3(64, 8),  64, 0, stream>>>(z0, W1, m1, mflag, z1, 4096,  2048, 256, 1);
        sparse_gemm_rf<<<dim3(128, 8), 64, 0, stream>>>(z1, W2, m2, mflag, z2, 8192,  4096, 512, 1);
        sparse_gemm_rf<<<dim3(256, 8), 64, 0, stream>>>(z2, W3, m3, mflag, z3, 16384, 8192, 1024, 1);
    }
}